// Round 1
// baseline (527.217 us; speedup 1.0000x reference)
//
#include <hip/hip_runtime.h>

// x: (8,1,1024,1024) f32, y: (8,12,1024,1024) f32, out: scalar f32
// loss = mean(|gather(y) - x|), gather per 4x4 pixel-shuffle cell:
//   c = (H%4)*4 + (W%4)
//   pred = y[b, CH[c], (H&~3)+RO[c], W]        (CO[c] == W%4 always)
// Includes the reference's _PERM[15]=5 bug: c=15 -> (ch=4, ro=0).

static constexpr unsigned QUADS = 8u * 1024u * 1024u / 4u; // 2,097,152

__global__ void zero_kernel(float* out) {
    if (threadIdx.x == 0 && blockIdx.x == 0) *out = 0.0f;
}

__global__ __launch_bounds__(256) void loss_kernel(
        const float* __restrict__ x, const float* __restrict__ y,
        float* __restrict__ out) {
    // nibble c of these packs = CH[c] / RO[c]
    const unsigned long long CH_PACK = 0x49A85241A7964130ULL;
    const unsigned long long RO_PACK = 0x0333222211110000ULL;

    unsigned t = blockIdx.x * 256u + threadIdx.x;   // one float4 of x per thread
    float acc = 0.0f;

    unsigned q    = t & 255u;          // quad index within row (W/4)
    unsigned hrow = (t >> 8) & 1023u;  // H  (wave-uniform: 256 quads per row)
    unsigned b    = t >> 18;           // batch
    unsigned w4   = q << 2;            // W base

    unsigned xoff = (((b << 10) | hrow) << 10) + w4;
    const float4 xv = *reinterpret_cast<const float4*>(x + xoff);

    unsigned rbase = hrow & ~3u;
    unsigned cbase = (hrow & 3u) << 2;

    float p[4];
#pragma unroll
    for (int j = 0; j < 4; ++j) {
        unsigned c  = cbase + (unsigned)j;
        unsigned ch = (unsigned)(CH_PACK >> (4u * c)) & 0xFu;
        unsigned ro = (unsigned)(RO_PACK >> (4u * c)) & 0xFu;
        unsigned yoff = ((((b * 12u + ch) << 10) + (rbase + ro)) << 10) + (w4 + (unsigned)j);
        p[j] = y[yoff];
    }

    acc = fabsf(p[0] - xv.x) + fabsf(p[1] - xv.y)
        + fabsf(p[2] - xv.z) + fabsf(p[3] - xv.w);

    // wave-64 shuffle reduction
#pragma unroll
    for (int off = 32; off > 0; off >>= 1)
        acc += __shfl_down(acc, off, 64);

    __shared__ float smem[4];
    unsigned lane = threadIdx.x & 63u;
    unsigned wid  = threadIdx.x >> 6;
    if (lane == 0) smem[wid] = acc;
    __syncthreads();

    if (threadIdx.x == 0) {
        float s = (smem[0] + smem[1]) + (smem[2] + smem[3]);
        atomicAdd(out, s * (1.0f / 8388608.0f));
    }
}

extern "C" void kernel_launch(void* const* d_in, const int* in_sizes, int n_in,
                              void* d_out, int out_size, void* d_ws, size_t ws_size,
                              hipStream_t stream) {
    const float* x = (const float*)d_in[0];
    const float* y = (const float*)d_in[1];
    float* out = (float*)d_out;

    hipLaunchKernelGGL(zero_kernel, dim3(1), dim3(64), 0, stream, out);
    // QUADS / 256 = 8192 blocks, no tail
    hipLaunchKernelGGL(loss_kernel, dim3(8192), dim3(256), 0, stream, x, y, out);
}

// Round 2
// 472.075 us; speedup vs baseline: 1.1168x; 1.1168x over previous
//
#include <hip/hip_runtime.h>

// x: (8,1,1024,1024) f32, y: (8,12,1024,1024) f32, out: scalar f32
// loss = mean(|gather(y) - x|), gather per 4x4 pixel-shuffle cell:
//   c = (H%4)*4 + (W%4)
//   pred = y[b, CH[c], (H&~3)+RO[c], W]        (CO[c] == W%4 always)
// Includes the reference's _PERM[15]=5 bug: c=15 -> (ch=4, ro=0).
//
// R1: replaced 8192 same-address atomicAdds (~490us serialization) with
// per-block partials in d_ws + a single-block final reduce.

#define NBLOCKS 8192

__global__ __launch_bounds__(256) void loss_partial_kernel(
        const float* __restrict__ x, const float* __restrict__ y,
        float* __restrict__ partial) {
    // nibble c of these packs = CH[c] / RO[c]
    const unsigned long long CH_PACK = 0x49A85241A7964130ULL;
    const unsigned long long RO_PACK = 0x0333222211110000ULL;

    unsigned t = blockIdx.x * 256u + threadIdx.x;   // one float4 of x per thread

    unsigned q    = t & 255u;          // quad index within row (W/4)
    unsigned hrow = (t >> 8) & 1023u;  // H  (wave-uniform: 256 quads per row)
    unsigned b    = t >> 18;           // batch
    unsigned w4   = q << 2;            // W base

    unsigned xoff = (((b << 10) | hrow) << 10) + w4;
    const float4 xv = *reinterpret_cast<const float4*>(x + xoff);

    unsigned rbase = hrow & ~3u;
    unsigned cbase = (hrow & 3u) << 2;

    float p[4];
#pragma unroll
    for (int j = 0; j < 4; ++j) {
        unsigned c  = cbase + (unsigned)j;
        unsigned ch = (unsigned)(CH_PACK >> (4u * c)) & 0xFu;
        unsigned ro = (unsigned)(RO_PACK >> (4u * c)) & 0xFu;
        unsigned yoff = ((((b * 12u + ch) << 10) + (rbase + ro)) << 10) + (w4 + (unsigned)j);
        p[j] = y[yoff];
    }

    float acc = fabsf(p[0] - xv.x) + fabsf(p[1] - xv.y)
              + fabsf(p[2] - xv.z) + fabsf(p[3] - xv.w);

    // wave-64 shuffle reduction
#pragma unroll
    for (int off = 32; off > 0; off >>= 1)
        acc += __shfl_down(acc, off, 64);

    __shared__ float smem[4];
    unsigned lane = threadIdx.x & 63u;
    unsigned wid  = threadIdx.x >> 6;
    if (lane == 0) smem[wid] = acc;
    __syncthreads();

    if (threadIdx.x == 0)
        partial[blockIdx.x] = (smem[0] + smem[1]) + (smem[2] + smem[3]);
}

__global__ __launch_bounds__(1024) void final_reduce_kernel(
        const float* __restrict__ partial, float* __restrict__ out) {
    unsigned t = threadIdx.x;  // 0..1023, 8192 partials = 2048 float4
    const float4* p4 = reinterpret_cast<const float4*>(partial);
    float4 a = p4[t];
    float4 b = p4[t + 1024];
    float acc = (a.x + a.y) + (a.z + a.w) + (b.x + b.y) + (b.z + b.w);

#pragma unroll
    for (int off = 32; off > 0; off >>= 1)
        acc += __shfl_down(acc, off, 64);

    __shared__ float smem[16];
    unsigned lane = t & 63u;
    unsigned wid  = t >> 6;
    if (lane == 0) smem[wid] = acc;
    __syncthreads();

    if (t == 0) {
        float s = 0.0f;
#pragma unroll
        for (int i = 0; i < 16; ++i) s += smem[i];
        *out = s * (1.0f / 8388608.0f);
    }
}

extern "C" void kernel_launch(void* const* d_in, const int* in_sizes, int n_in,
                              void* d_out, int out_size, void* d_ws, size_t ws_size,
                              hipStream_t stream) {
    const float* x = (const float*)d_in[0];
    const float* y = (const float*)d_in[1];
    float* out     = (float*)d_out;
    float* partial = (float*)d_ws;   // 8192 floats = 32 KB

    hipLaunchKernelGGL(loss_partial_kernel, dim3(NBLOCKS), dim3(256), 0, stream,
                       x, y, partial);
    hipLaunchKernelGGL(final_reduce_kernel, dim3(1), dim3(1024), 0, stream,
                       partial, out);
}